// Round 4
// baseline (218.864 us; speedup 1.0000x reference)
//
#include <hip/hip_runtime.h>
#include <stdint.h>

// ---------------- modular arithmetic (Montgomery, R = 2^32) ----------------
static constexpr uint32_t P = 2013265921u;         // 15*2^27 + 1
static constexpr int      LOGM = 11;               // per-block DFT size 2048
static constexpr int      MSZ  = 1 << LOGM;

__host__ __device__ constexpr uint32_t neg_pinv32() {
    uint32_t x = 1u;
    for (int i = 0; i < 5; ++i) x *= 2u - P * x;
    return 0u - x;
}
static constexpr uint32_t NEG_PINV = neg_pinv32();
static constexpr uint32_t R1 = (uint32_t)(((uint64_t)1 << 32) % P);
static constexpr uint32_t R2 = (uint32_t)(((uint64_t)R1 * R1) % P);

// REDC with the identity low32(t + m*P) == 0, carry == (t_lo != 0):
// r = t_hi + umulhi(m, P) + (t_lo != 0)  ->  6 VALU + 2-op reduce.
__device__ __forceinline__ uint32_t mont_mul(uint32_t a, uint32_t b) {
    uint32_t tlo = a * b;
    uint32_t thi = __umulhi(a, b);
    uint32_t m   = tlo * NEG_PINV;
    uint32_t r   = thi + __umulhi(m, P) + (tlo != 0u);   // r < 2P
    uint32_t s   = r - P;
    return s < r ? s : r;                                 // min-trick
}
__device__ __forceinline__ uint32_t to_mont(uint32_t a) { return mont_mul(a, R2); }
__device__ __forceinline__ uint32_t add_p(uint32_t a, uint32_t b) {
    uint32_t r = a + b, s = r - P; return s < r ? s : r;
}
__device__ __forceinline__ uint32_t sub_p(uint32_t a, uint32_t b) {
    uint32_t r = a - b, s = r + P; return s < r ? s : r;
}
__device__ __forceinline__ uint4 mm4(uint32_t w, uint4 v) {
    return make_uint4(mont_mul(w, v.x), mont_mul(w, v.y),
                      mont_mul(w, v.z), mont_mul(w, v.w));
}
__device__ __forceinline__ void bf4(uint4& L, uint4& H, uint32_t w) {
    uint4 t = mm4(w, H);
    uint4 l = L;
    L = make_uint4(add_p(l.x, t.x), add_p(l.y, t.y), add_p(l.z, t.z), add_p(l.w, t.w));
    H = make_uint4(sub_p(l.x, t.x), sub_p(l.y, t.y), sub_p(l.z, t.z), sub_p(l.w, t.w));
}

// nontemporal 16B store (pass-2 epilogue: written once, never re-read)
typedef unsigned int u32v4 __attribute__((ext_vector_type(4)));
__device__ __forceinline__ void nt_store16(uint4* p, uint4 v) {
    u32v4 w; w.x = v.x; w.y = v.y; w.z = v.z; w.w = v.w;
    __builtin_nontemporal_store(w, (u32v4*)p);
}

// Element swizzle: conflict-free for strides 1/8/64/512 (el&7 distinct across
// each aligned 4-sub run; x2 column packing preserves bank spread).
__device__ __forceinline__ int g_sw(int el) {
    return el ^ (((el >> 3) ^ (el >> 6)) & 7);
}
__device__ __forceinline__ int fidx(int el, int c2) { return (g_sw(el) << 1) | c2; }

// 3 DIT stages (radix-8) in registers.
__device__ __forceinline__ void radix8(uint4 x[8],
        uint32_t ta, uint32_t tb0, uint32_t tb1,
        uint32_t tc0, uint32_t tc1, uint32_t tc2, uint32_t tc3) {
    bf4(x[0], x[1], ta);  bf4(x[2], x[3], ta);
    bf4(x[4], x[5], ta);  bf4(x[6], x[7], ta);
    bf4(x[0], x[2], tb0); bf4(x[1], x[3], tb1);
    bf4(x[4], x[6], tb0); bf4(x[5], x[7], tb1);
    bf4(x[0], x[4], tc0); bf4(x[1], x[5], tc1);
    bf4(x[2], x[6], tc2); bf4(x[3], x[7], tc3);
}

// One block = 512 threads = TWO 2048-pt inverse DFTs (72 KiB LDS -> 2
// blocks/CU: two independent barrier domains overlap each other's drains).
// Thread t: c2 = t&1 selects the transform (global col c = 2*grp + c2),
// sub = t>>1 owns 8 elements. Adjacent lane pairs cover 32B of each line.
// PASS1: read x[row*2048 + c] (bit-rev folded), write Y[c*2048+k2]*w^(c*k2).
// PASS2: read Y[i1*2048 + c], write out[k1*2048 + c]*n_inv (in-place safe:
//        same per-column address set, columns disjoint across blocks).
template <bool PASS2>
__global__ __launch_bounds__(512, 4) void intt_pass(
        const uint4* __restrict__ src, uint4* __restrict__ dst,
        const uint32_t* __restrict__ tw,
        const uint32_t* __restrict__ ninv_p)
{
    __shared__ uint4    buf[MSZ * 2];      // 64 KiB
    __shared__ uint32_t stab[2048];        // 8 KiB; stage s at [2^(s-1)-1 .. )

    const int      t   = threadIdx.x;
    const int      c2  = t & 1;
    const int      sub = t >> 1;           // [0,256)
    const uint32_t bid = blockIdx.x;
    // XCD swizzle: XCD x handles a contiguous 128-grp (256-column) range,
    // so paired columns (sharing 64B lines) stay within one XCD's L2.
    const uint32_t grp = ((bid & 7u) << 7) | (bid >> 3);   // [0,1024)
    const uint32_t c   = (grp << 1) | (uint32_t)c2;        // global column

    // per-stage twiddle table: stab[2^(s-1)-1 + j] = Mont(W^(j*2^(11-s))),
    // W = w^2048. Entry e: e+1 = 2^(s-1)+j  ->  tw[j << (21-(s-1))].
#pragma unroll
    for (int q = 0; q < 4; ++q) {
        int e = t + (q << 9);
        if (e < 2047) {
            uint32_t ep1 = (uint32_t)e + 1u;
            int sm1 = 31 - __clz((int)ep1);            // s-1
            uint32_t j = ep1 - (1u << sm1);
            stab[e] = to_mont(tw[j << (21 - sm1)]);
        }
    }

    // global gather, bit-reversal folded in: el = 8*sub+m <- row rev11(el)
    const uint32_t r8 = __brev((uint32_t)sub) >> 24;
    uint4 x[8];
#pragma unroll
    for (int m = 0; m < 8; ++m) {
        uint32_t r3 = __brev((uint32_t)m) >> 29;
        x[m] = src[((r3 << 8) | r8) * (uint32_t)MSZ + c];
    }
    __syncthreads();   // stab ready

    // ---- phase 0: stages 1-3 (j = 0) ----
    radix8(x, stab[0], stab[1], stab[2], stab[3], stab[4], stab[5], stab[6]);
#pragma unroll
    for (int m = 0; m < 8; ++m) buf[fidx(8 * sub + m, c2)] = x[m];
    __syncthreads();

    // ---- phase 1: stages 4-6 (element stride 8) ----
    {
        const int L = sub & 7, hi = sub >> 3;
        const int base = (hi << 6) | L;
#pragma unroll
        for (int m = 0; m < 8; ++m) x[m] = buf[fidx(base | (m << 3), c2)];
        radix8(x, stab[7 + L], stab[15 + L], stab[23 + L],
                  stab[31 + L], stab[39 + L], stab[47 + L], stab[55 + L]);
#pragma unroll
        for (int m = 0; m < 8; ++m) buf[fidx(base | (m << 3), c2)] = x[m];
    }
    __syncthreads();

    // ---- phase 2: stages 7-9 (element stride 64) ----
    {
        const int L = sub & 63, hi = sub >> 6;
        const int base = (hi << 9) | L;
#pragma unroll
        for (int m = 0; m < 8; ++m) x[m] = buf[fidx(base | (m << 6), c2)];
        radix8(x, stab[63 + L], stab[127 + L], stab[191 + L],
                  stab[255 + L], stab[319 + L], stab[383 + L], stab[447 + L]);
#pragma unroll
        for (int m = 0; m < 8; ++m) buf[fidx(base | (m << 6), c2)] = x[m];
    }
    __syncthreads();

    // ---- phase 3: stages 10-11 (stride 512) + epilogue ----
    uint32_t nm = 0u, s256 = 0u, step512 = 0u, tm0 = 0u;
    if (PASS2) {
        nm = to_mont(*ninv_p);
    } else {
        s256    = to_mont(tw[c << 8]);              // Mont(w^(256c)), exp < 2^19
        step512 = mont_mul(s256, s256);             // Mont(w^(512c))
        tm0     = to_mont(tw[c * (uint32_t)sub]);   // Mont(w^(c*sub)), exp < 2^19
    }
#pragma unroll
    for (int gg = 0; gg < 2; ++gg) {
        const int lo = sub + (gg << 8);             // [0,512)
        uint4 y[4];
#pragma unroll
        for (int m = 0; m < 4; ++m) y[m] = buf[fidx(lo | (m << 9), c2)];
        const uint32_t t10  = stab[511 + lo];
        const uint32_t t110 = stab[1023 + lo];
        const uint32_t t111 = stab[1535 + lo];
        bf4(y[0], y[1], t10);  bf4(y[2], y[3], t10);
        bf4(y[0], y[2], t110); bf4(y[1], y[3], t111);

        if (!PASS2) {
            uint32_t tm = tm0;                      // Mont(w^(c*lo))
#pragma unroll
            for (int m = 0; m < 4; ++m) {
                dst[c * (uint32_t)MSZ + (uint32_t)((m << 9) | lo)] = mm4(tm, y[m]);
                tm = mont_mul(tm, step512);
            }
            tm0 = mont_mul(tm0, s256);              // advance lo by 256 for gg=1
        } else {
#pragma unroll
            for (int m = 0; m < 4; ++m)
                nt_store16(&dst[(uint32_t)((m << 9) | lo) * (uint32_t)MSZ + c],
                           mm4(nm, y[m]));
        }
    }
}

// ------------------------------- launch ------------------------------------
extern "C" void kernel_launch(void* const* d_in, const int* in_sizes, int n_in,
                              void* d_out, int out_size, void* d_ws, size_t ws_size,
                              hipStream_t stream)
{
    const uint4*    x    = (const uint4*)d_in[0];      // (N, 4) int32 rows
    const uint32_t* tw   = (const uint32_t*)d_in[1];   // w^k, k < 2^21
    const uint32_t* ninv = (const uint32_t*)d_in[2];
    uint4*          out  = (uint4*)d_out;

    intt_pass<false><<<dim3(1024), dim3(512), 0, stream>>>(x, out, tw, ninv);
    intt_pass<true ><<<dim3(1024), dim3(512), 0, stream>>>(out, out, tw, ninv);
}

// Round 5
// 201.183 us; speedup vs baseline: 1.0879x; 1.0879x over previous
//
#include <hip/hip_runtime.h>
#include <stdint.h>

// ---------------- modular arithmetic ----------------
static constexpr uint32_t P = 2013265921u;         // 15*2^27 + 1
static constexpr int      LOGM = 11;               // per-block DFT size 2048
static constexpr int      MSZ  = 1 << LOGM;
static constexpr int      NCOL = 4;                // batch columns per block

__host__ __device__ constexpr uint32_t neg_pinv32() {
    uint32_t x = 1u;
    for (int i = 0; i < 5; ++i) x *= 2u - P * x;
    return 0u - x;
}
static constexpr uint32_t NEG_PINV = neg_pinv32();
static constexpr uint32_t R1 = (uint32_t)(((uint64_t)1 << 32) % P);
static constexpr uint32_t R2 = (uint32_t)(((uint64_t)R1 * R1) % P);

// Montgomery (R=2^32). mont_mul(plain, Mont(w)) = plain*w  — used for the
// epilogue twiddle chains and the 5 non-trivial phase-0 butterflies.
__device__ __forceinline__ uint32_t mont_mul(uint32_t a, uint32_t b) {
    uint32_t tlo = a * b;
    uint32_t thi = __umulhi(a, b);
    uint32_t m   = tlo * NEG_PINV;
    uint32_t r   = thi + __umulhi(m, P) + (tlo != 0u);   // r < 2P
    uint32_t s   = r - P;
    return s < r ? s : r;
}
__device__ __forceinline__ uint32_t to_mont(uint32_t a) { return mont_mul(a, R2); }

// Shoup mult by precomputed (w, w'=floor(w*2^32/P)): 4 ops + 2-op reduce.
__device__ __forceinline__ uint32_t shoup_mul(uint32_t w, uint32_t wp, uint32_t x) {
    uint32_t q = __umulhi(wp, x);
    uint32_t t = w * x - q * P;          // exact: t in [0, 2P) < 2^32
    uint32_t s = t - P;
    return s < t ? s : t;
}
__device__ __forceinline__ uint32_t add_p(uint32_t a, uint32_t b) {
    uint32_t r = a + b, s = r - P; return s < r ? s : r;
}
__device__ __forceinline__ uint32_t sub_p(uint32_t a, uint32_t b) {
    uint32_t r = a - b, s = r + P; return s < r ? s : r;
}
__device__ __forceinline__ uint4 mm4(uint32_t w, uint4 v) {   // Montgomery x4
    return make_uint4(mont_mul(w, v.x), mont_mul(w, v.y),
                      mont_mul(w, v.z), mont_mul(w, v.w));
}
// butterfly variants (all keep values canonical [0,P))
__device__ __forceinline__ void bf4_sh(uint4& L, uint4& H, uint2 w) {
    uint4 t = make_uint4(shoup_mul(w.x, w.y, H.x), shoup_mul(w.x, w.y, H.y),
                         shoup_mul(w.x, w.y, H.z), shoup_mul(w.x, w.y, H.w));
    uint4 l = L;
    L = make_uint4(add_p(l.x, t.x), add_p(l.y, t.y), add_p(l.z, t.z), add_p(l.w, t.w));
    H = make_uint4(sub_p(l.x, t.x), sub_p(l.y, t.y), sub_p(l.z, t.z), sub_p(l.w, t.w));
}
__device__ __forceinline__ void bf4_mont(uint4& L, uint4& H, uint32_t wm) {
    uint4 t = mm4(wm, H);
    uint4 l = L;
    L = make_uint4(add_p(l.x, t.x), add_p(l.y, t.y), add_p(l.z, t.z), add_p(l.w, t.w));
    H = make_uint4(sub_p(l.x, t.x), sub_p(l.y, t.y), sub_p(l.z, t.z), sub_p(l.w, t.w));
}
__device__ __forceinline__ void bf4_triv(uint4& L, uint4& H) {   // w == 1
    uint4 l = L, h = H;
    L = make_uint4(add_p(l.x, h.x), add_p(l.y, h.y), add_p(l.z, h.z), add_p(l.w, h.w));
    H = make_uint4(sub_p(l.x, h.x), sub_p(l.y, h.y), sub_p(l.z, h.z), sub_p(l.w, h.w));
}

// LDS element swizzle: conflict-free for strides 1/8/64/512.
__device__ __forceinline__ int g_sw(int el) {
    return el ^ (((el >> 3) ^ (el >> 6)) & 7);
}
__device__ __forceinline__ int fidx(int el, int c4) { return (g_sw(el) << 2) | c4; }

// 3 DIT stages (radix-8) with Shoup twiddles (phases 1-2).
__device__ __forceinline__ void radix8_sh(uint4 x[8],
        uint2 ta, uint2 tb0, uint2 tb1,
        uint2 tc0, uint2 tc1, uint2 tc2, uint2 tc3) {
    bf4_sh(x[0], x[1], ta);  bf4_sh(x[2], x[3], ta);
    bf4_sh(x[4], x[5], ta);  bf4_sh(x[6], x[7], ta);
    bf4_sh(x[0], x[2], tb0); bf4_sh(x[1], x[3], tb1);
    bf4_sh(x[4], x[6], tb0); bf4_sh(x[5], x[7], tb1);
    bf4_sh(x[0], x[4], tc0); bf4_sh(x[1], x[5], tc1);
    bf4_sh(x[2], x[6], tc2); bf4_sh(x[3], x[7], tc3);
}

// One block = 1024 threads = one 2048-pt inverse DFT over 4 adjacent columns.
// c4 = t&3 (global col c = 4*grp + c4), sub = t>>2 owns 8 elements; 4
// consecutive lanes = one full 64B line on every scattered global access.
template <bool PASS2>
__global__ __launch_bounds__(1024, 2) void intt_pass(
        const uint4* __restrict__ src, uint4* __restrict__ dst,
        const uint32_t* __restrict__ tw,
        const uint32_t* __restrict__ ninv_p)
{
    __shared__ uint4 buf[MSZ * NCOL];   // 128 KiB
    __shared__ uint2 stab[2048];        // 16 KiB (w, w_shoup); stage s at 2^(s-1)-1

    const int      t   = threadIdx.x;
    const int      c4  = t & 3;
    const int      sub = t >> 2;           // [0,256)
    const uint32_t bid = blockIdx.x;
    const uint32_t grp = ((bid & 7u) << 6) | (bid >> 3);   // XCD swizzle
    const uint32_t c   = (grp << 2) | (uint32_t)c4;        // global column

    // stage-twiddle table build (2 entries/thread): plain w + Shoup companion.
    // stab[2^(s-1)-1 + j] = W^(j*2^(11-s)), W = w^2048 -> tw[j << (21-(s-1))].
    uint32_t wv[2]; int ev[2];
#pragma unroll
    for (int q = 0; q < 2; ++q) {
        int e = t + (q << 10);
        ev[q] = e;
        if (e < 2047) {
            uint32_t ep1 = (uint32_t)e + 1u;
            int sm1 = 31 - __clz((int)ep1);
            uint32_t j = ep1 - (1u << sm1);
            wv[q] = tw[j << (21 - sm1)];
        }
    }

    // global gather, bit-reversal folded in: el = 8*sub+m <- row rev11(el)
    const uint32_t r8 = __brev((uint32_t)sub) >> 24;
    uint4 x[8];
#pragma unroll
    for (int m = 0; m < 8; ++m) {
        uint32_t r3 = __brev((uint32_t)m) >> 29;
        x[m] = src[((r3 << 8) | r8) * (uint32_t)MSZ + c];
    }

    // finish stab (64-bit div overlaps the gather latency)
#pragma unroll
    for (int q = 0; q < 2; ++q) {
        if (ev[q] < 2047) {
            uint32_t w  = wv[q];
            uint32_t wp = (uint32_t)((((uint64_t)w) << 32) / P);
            stab[ev[q]] = make_uint2(w, wp);
        }
    }

    // phase-0 non-trivial twiddles (uniform): u1=W^512, u2=W^256, u3=W^768
    const uint32_t u1 = to_mont(tw[1u << 20]);
    const uint32_t u2 = to_mont(tw[1u << 19]);
    const uint32_t u3 = to_mont(tw[3u << 19]);

    // ---- phase 0: stages 1-3, j=0 group (7 of 12 butterflies are w=1) ----
    bf4_triv(x[0], x[1]);  bf4_triv(x[2], x[3]);
    bf4_triv(x[4], x[5]);  bf4_triv(x[6], x[7]);
    bf4_triv(x[0], x[2]);  bf4_mont(x[1], x[3], u1);
    bf4_triv(x[4], x[6]);  bf4_mont(x[5], x[7], u1);
    bf4_triv(x[0], x[4]);  bf4_mont(x[1], x[5], u2);
    bf4_mont(x[2], x[6], u1); bf4_mont(x[3], x[7], u3);
#pragma unroll
    for (int m = 0; m < 8; ++m) buf[fidx(8 * sub + m, c4)] = x[m];
    __syncthreads();   // covers stab AND phase-0 buf

    // ---- phase 1: stages 4-6 (element stride 8) ----
    {
        const int L = sub & 7, hi = sub >> 3;
        const int base = (hi << 6) | L;
#pragma unroll
        for (int m = 0; m < 8; ++m) x[m] = buf[fidx(base | (m << 3), c4)];
        radix8_sh(x, stab[7 + L], stab[15 + L], stab[23 + L],
                     stab[31 + L], stab[39 + L], stab[47 + L], stab[55 + L]);
#pragma unroll
        for (int m = 0; m < 8; ++m) buf[fidx(base | (m << 3), c4)] = x[m];
    }
    __syncthreads();

    // ---- phase 2: stages 7-9 (element stride 64) ----
    {
        const int L = sub & 63, hi = sub >> 6;
        const int base = (hi << 9) | L;
#pragma unroll
        for (int m = 0; m < 8; ++m) x[m] = buf[fidx(base | (m << 6), c4)];
        radix8_sh(x, stab[63 + L], stab[127 + L], stab[191 + L],
                     stab[255 + L], stab[319 + L], stab[383 + L], stab[447 + L]);
#pragma unroll
        for (int m = 0; m < 8; ++m) buf[fidx(base | (m << 6), c4)] = x[m];
    }
    __syncthreads();

    // ---- phase 3: stages 10-11 (stride 512) + epilogue ----
    uint32_t nm = 0u, s256 = 0u, step512 = 0u, tm0 = 0u;
    if (PASS2) {
        nm = to_mont(*ninv_p);
    } else {
        s256    = to_mont(tw[c << 8]);              // Mont(w^(256c))
        step512 = mont_mul(s256, s256);             // Mont(w^(512c))
        tm0     = to_mont(tw[c * (uint32_t)sub]);   // Mont(w^(c*sub)), exp<2^19
    }
#pragma unroll
    for (int gg = 0; gg < 2; ++gg) {
        const int lo = sub + (gg << 8);             // [0,512)
        uint4 y[4];
#pragma unroll
        for (int m = 0; m < 4; ++m) y[m] = buf[fidx(lo | (m << 9), c4)];
        const uint2 t10  = stab[511 + lo];
        const uint2 t110 = stab[1023 + lo];
        const uint2 t111 = stab[1535 + lo];
        bf4_sh(y[0], y[1], t10);  bf4_sh(y[2], y[3], t10);
        bf4_sh(y[0], y[2], t110); bf4_sh(y[1], y[3], t111);

        if (!PASS2) {
            uint32_t tm = tm0;                      // Mont(w^(c*lo))
#pragma unroll
            for (int m = 0; m < 4; ++m) {
                dst[c * (uint32_t)MSZ + (uint32_t)((m << 9) | lo)] = mm4(tm, y[m]);
                tm = mont_mul(tm, step512);
            }
            tm0 = mont_mul(tm0, s256);              // advance lo by 256
        } else {
#pragma unroll
            for (int m = 0; m < 4; ++m)
                dst[(uint32_t)((m << 9) | lo) * (uint32_t)MSZ + c] = mm4(nm, y[m]);
        }
    }
}

// ------------------------------- launch ------------------------------------
extern "C" void kernel_launch(void* const* d_in, const int* in_sizes, int n_in,
                              void* d_out, int out_size, void* d_ws, size_t ws_size,
                              hipStream_t stream)
{
    const uint4*    x    = (const uint4*)d_in[0];      // (N, 4) int32 rows
    const uint32_t* tw   = (const uint32_t*)d_in[1];   // w^k, k < 2^21
    const uint32_t* ninv = (const uint32_t*)d_in[2];
    uint4*          out  = (uint4*)d_out;

    intt_pass<false><<<dim3(512), dim3(1024), 0, stream>>>(x, out, tw, ninv);
    intt_pass<true ><<<dim3(512), dim3(1024), 0, stream>>>(out, out, tw, ninv);
}